// Round 1
// baseline (412.808 us; speedup 1.0000x reference)
//
#include <hip/hip_runtime.h>
#include <hip/hip_bf16.h>

#define N_NODES 50000
#define NREL 16
#define HID 64
#define NCLS 16
#define NBKT (N_NODES * NREL)       // 800000 buckets (dst*16 + rel)
#define SB 2048                     // scan elems per block
#define NSB ((NBKT + SB - 1) / SB)  // 391
#define TILE 32                     // dst nodes per fused block
#define NTB ((N_NODES + TILE - 1) / TILE)  // 1563
#define XCHUNKS (N_NODES * HID / 8)        // 400000
#define W1N (17 * HID * HID)               // 69632
#define W2N (17 * NCLS * HID)              // 17408

typedef __attribute__((ext_vector_type(8))) short bf16x8;
typedef __attribute__((ext_vector_type(4))) float f32x4;

static __device__ __forceinline__ unsigned short f2bf(float f) {
    __hip_bfloat16 h = __float2bfloat16(f);
    return *reinterpret_cast<unsigned short*>(&h);
}
static __device__ __forceinline__ float bf2f(unsigned short u) {
    __hip_bfloat16 h;
    *reinterpret_cast<unsigned short*>(&h) = u;
    return __bfloat162float(h);
}

// ---------------------------------------------------------------------------
// ws layout:
//   bcnt/rstart i32[800020] (zeroed; scan3 -> prefix IN PLACE)
//   | rank i32[E] | bsum i32[512] | sedge i32[E] (src only; rel implied by bucket)
//   | WbT1 bf16[17*64*64] [t][n][k] | WbT2 bf16[17*16*64] [t][n][k]
//   | xb bf16[50000*64] | X1b bf16[50000*64]
// Aggregate-then-transform: H1/H2 dense intermediates eliminated; per-tile
// relation A-tiles live in LDS only.
// ---------------------------------------------------------------------------

// K0: convert x -> bf16 AND build transposed bf16 weights (merged grid)
__global__ __launch_bounds__(256) void cvt_k(const float* __restrict__ x,
                                             const float* __restrict__ W1,
                                             const float* __restrict__ root1,
                                             const float* __restrict__ W2,
                                             const float* __restrict__ root2,
                                             ushort* __restrict__ xb,
                                             ushort* __restrict__ WbT1,
                                             ushort* __restrict__ WbT2) {
    int i = blockIdx.x * 256 + threadIdx.x;
    if (i < XCHUNKS) {
        float4 f0 = *(const float4*)(x + (size_t)i * 8);
        float4 f1 = *(const float4*)(x + (size_t)i * 8 + 4);
        bf16x8 o;
        o[0] = (short)f2bf(f0.x); o[1] = (short)f2bf(f0.y);
        o[2] = (short)f2bf(f0.z); o[3] = (short)f2bf(f0.w);
        o[4] = (short)f2bf(f1.x); o[5] = (short)f2bf(f1.y);
        o[6] = (short)f2bf(f1.z); o[7] = (short)f2bf(f1.w);
        *(bf16x8*)(xb + (size_t)i * 8) = o;
    } else {
        int j = i - XCHUNKS;
        if (j < W1N) {
            int t = j >> 12, rem = j & 4095, n = rem >> 6, k = rem & 63;
            float v = (t < 16) ? W1[(size_t)t * HID * HID + k * HID + n]
                               : root1[k * HID + n];
            WbT1[j] = f2bf(v);
        } else {
            int m = j - W1N;
            if (m < W2N) {
                int t = m >> 10, rem = m & 1023, n = rem >> 6, k = rem & 63;
                float v = (t < 16) ? W2[(size_t)t * HID * NCLS + k * NCLS + n]
                                   : root2[k * NCLS + n];
                WbT2[m] = f2bf(v);
            }
        }
    }
}

// K1: one atomic pass over buckets (dst*16+rel): count + per-edge rank
__global__ __launch_bounds__(256) void rank_k(const int* __restrict__ dstp,
                                              const int* __restrict__ et,
                                              int* __restrict__ bcnt,
                                              int* __restrict__ rank, int E) {
    int i = blockIdx.x * 256 + threadIdx.x;
    if (i < E) {
        int b = dstp[i] * NREL + et[i];
        rank[i] = atomicAdd(&bcnt[b], 1);
    }
}

// K2a: per-block sums of bcnt (2048 elems / block, 8 per thread)
__global__ __launch_bounds__(256) void scan1_k(const int* __restrict__ bcnt,
                                               int* __restrict__ bsum) {
    int b = blockIdx.x, t = threadIdx.x;
    int base = b * SB + t * 8;
    int s = 0;
#pragma unroll
    for (int j = 0; j < 8; ++j)
        if (base + j < NBKT) s += bcnt[base + j];
#pragma unroll
    for (int off = 1; off < 64; off <<= 1) s += __shfl_xor(s, off, 64);
    __shared__ int ws[4];
    if ((t & 63) == 0) ws[t >> 6] = s;
    __syncthreads();
    if (t == 0) bsum[b] = ws[0] + ws[1] + ws[2] + ws[3];
}

// K2b: exclusive scan of bsum[NSB] (one 512-thread block); rstart[NBKT] = E
__global__ __launch_bounds__(512) void scan2_k(int* __restrict__ bsum,
                                               int* __restrict__ rstart, int E) {
    __shared__ int ts[512];
    int t = threadIdx.x;
    int v = (t < NSB) ? bsum[t] : 0;
    ts[t] = v;
    __syncthreads();
    int acc = v;
    for (int off = 1; off < 512; off <<= 1) {
        int u = (t >= off) ? ts[t - off] : 0;
        __syncthreads();
        acc += u;
        ts[t] = acc;
        __syncthreads();
    }
    if (t < NSB) bsum[t] = acc - v;
    if (t == 0) rstart[NBKT] = E;
}

// K2c: per-block exclusive scan, IN PLACE (bcnt -> rstart)
__global__ __launch_bounds__(256) void scan3_k(int* __restrict__ bcnt,
                                               const int* __restrict__ bsum) {
    int b = blockIdx.x, t = threadIdx.x;
    int base = b * SB + t * 8;
    int a[8];
    int s = 0;
#pragma unroll
    for (int j = 0; j < 8; ++j) {
        a[j] = (base + j < NBKT) ? bcnt[base + j] : 0;
        s += a[j];
    }
    __shared__ int ts[256];
    ts[t] = s;
    __syncthreads();
    int acc = s;
    for (int off = 1; off < 256; off <<= 1) {
        int u = (t >= off) ? ts[t - off] : 0;
        __syncthreads();
        acc += u;
        ts[t] = acc;
        __syncthreads();
    }
    int run = bsum[b] + (acc - s);
#pragma unroll
    for (int j = 0; j < 8; ++j) {
        if (base + j < NBKT) bcnt[base + j] = run;
        run += a[j];
    }
}

// K3: atomic-free scatter (src only; inv & used no longer needed)
__global__ __launch_bounds__(256) void scat_k(const int* __restrict__ srcp,
                                              const int* __restrict__ dstp,
                                              const int* __restrict__ et,
                                              const int* __restrict__ rank,
                                              const int* __restrict__ rstart,
                                              int* __restrict__ sedge, int E) {
    int i = blockIdx.x * 256 + threadIdx.x;
    if (i < E) {
        int b = dstp[i] * NREL + et[i];
        sedge[rstart[b] + rank[i]] = srcp[i];
    }
}

// ---------------------------------------------------------------------------
// Fused layer kernels: per 32-dst tile, build A[17][32][64] bf16 in LDS
// (16 relation means + root rows), then MFMA against all 17 weight slices.
// LDS rows are 128 B -> XOR swizzle byte^=((row&7)<<4) on both sides to kill
// the 16-way ds_read_b128 bank conflict (residual 2-way = free).
// ---------------------------------------------------------------------------

__global__ __launch_bounds__(256) void fuse1_k(const ushort* __restrict__ xb,
                                               const int* __restrict__ sedge,
                                               const int* __restrict__ rstart,
                                               const ushort* __restrict__ WbT1,
                                               const float* __restrict__ b1,
                                               ushort* __restrict__ X1b) {
    __shared__ bf16x8 Abuf[17 * TILE * 8];  // 69632 B
    char* Ab = (char*)Abuf;
    int tid = threadIdx.x;
    int dst0 = blockIdx.x * TILE;

    // --- root tile (t = 16): A[16][row][:] = xb[dst0+row][:]
    {
        int row = tid >> 3, ch = tid & 7;  // 32 rows x 8 chunks of 16B
        int node = dst0 + row;
        bf16x8 v = {0, 0, 0, 0, 0, 0, 0, 0};
        if (node < N_NODES) v = *(const bf16x8*)(xb + (size_t)node * HID + ch * 8);
        int addr = (((16 * TILE + row) << 7) + (ch << 4)) ^ ((row & 7) << 4);
        *(bf16x8*)(Ab + addr) = v;
    }

    // --- gather/aggregate: group g (=dst row) x 8 lanes (8 cols each);
    // buckets for row g are contiguous, hi of bucket r == lo of bucket r+1.
    {
        int g = tid >> 3, l8 = tid & 7;
        int node = dst0 + g;
        bool valid = node < N_NODES;
        const ushort* xcol = xb + l8 * 8;
        int lo = valid ? rstart[node * NREL] : 0;
        for (int r = 0; r < NREL; ++r) {
            int hi = valid ? rstart[node * NREL + r + 1] : 0;
            float acc[8] = {0.f, 0.f, 0.f, 0.f, 0.f, 0.f, 0.f, 0.f};
            int cnt = hi - lo;
            for (int e = lo; e < hi; ++e) {
                int src = sedge[e];
                bf16x8 v = *(const bf16x8*)(xcol + (size_t)src * HID);
#pragma unroll
                for (int j = 0; j < 8; ++j) acc[j] += bf2f((unsigned short)v[j]);
            }
            float s = (cnt > 0) ? 1.0f / (float)cnt : 0.0f;
            bf16x8 o;
#pragma unroll
            for (int j = 0; j < 8; ++j) o[j] = (short)f2bf(acc[j] * s);
            int addr = (((r * TILE + g) << 7) + (l8 << 4)) ^ ((g & 7) << 4);
            *(bf16x8*)(Ab + addr) = o;
            lo = hi;
        }
    }
    __syncthreads();

    // --- MFMA: wave w owns out cols [w*16, w*16+16), both 16-row m-tiles
    int wave = tid >> 6, lane = tid & 63;
    int mr = lane & 15, kq = lane >> 4;
    f32x4 c0 = {0.f, 0.f, 0.f, 0.f}, c1 = {0.f, 0.f, 0.f, 0.f};
    const ushort* wb = WbT1 + (wave * 16 + mr) * HID + kq * 8;
    int sw = (mr & 7) << 4;
    int a00o = ((mr << 7) + (kq << 4)) ^ sw;
    int a01o = ((mr << 7) + 64 + (kq << 4)) ^ sw;
    int a10o = (((16 + mr) << 7) + (kq << 4)) ^ sw;   // (16+mr)&7 == mr&7
    int a11o = (((16 + mr) << 7) + 64 + (kq << 4)) ^ sw;
    for (int t = 0; t < 17; ++t) {
        bf16x8 bk0 = *(const bf16x8*)(wb + t * 4096);
        bf16x8 bk1 = *(const bf16x8*)(wb + t * 4096 + 32);
        const char* At = Ab + t * (TILE * 128);
        bf16x8 a00 = *(const bf16x8*)(At + a00o);
        bf16x8 a01 = *(const bf16x8*)(At + a01o);
        bf16x8 a10 = *(const bf16x8*)(At + a10o);
        bf16x8 a11 = *(const bf16x8*)(At + a11o);
        c0 = __builtin_amdgcn_mfma_f32_16x16x32_bf16(a00, bk0, c0, 0, 0, 0);
        c0 = __builtin_amdgcn_mfma_f32_16x16x32_bf16(a01, bk1, c0, 0, 0, 0);
        c1 = __builtin_amdgcn_mfma_f32_16x16x32_bf16(a10, bk0, c1, 0, 0, 0);
        c1 = __builtin_amdgcn_mfma_f32_16x16x32_bf16(a11, bk1, c1, 0, 0, 0);
    }
    float bias = b1[wave * 16 + mr];
    int col = wave * 16 + mr;
#pragma unroll
    for (int j = 0; j < 4; ++j) {
        int r0 = dst0 + kq * 4 + j;  // D row = quad*4+reg
        if (r0 < N_NODES)
            X1b[(size_t)r0 * HID + col] = f2bf(fmaxf(c0[j] + bias, 0.f));
        int r1 = r0 + 16;
        if (r1 < N_NODES)
            X1b[(size_t)r1 * HID + col] = f2bf(fmaxf(c1[j] + bias, 0.f));
    }
}

__global__ __launch_bounds__(256) void fuse2_k(const ushort* __restrict__ X1b,
                                               const int* __restrict__ sedge,
                                               const int* __restrict__ rstart,
                                               const ushort* __restrict__ WbT2,
                                               const float* __restrict__ b2,
                                               float* __restrict__ out) {
    __shared__ bf16x8 Abuf[17 * TILE * 8];  // 69632 B
    __shared__ float P[4 * TILE * NCLS];    // 8192 B partials (per-wave)
    char* Ab = (char*)Abuf;
    int tid = threadIdx.x;
    int dst0 = blockIdx.x * TILE;

    {
        int row = tid >> 3, ch = tid & 7;
        int node = dst0 + row;
        bf16x8 v = {0, 0, 0, 0, 0, 0, 0, 0};
        if (node < N_NODES) v = *(const bf16x8*)(X1b + (size_t)node * HID + ch * 8);
        int addr = (((16 * TILE + row) << 7) + (ch << 4)) ^ ((row & 7) << 4);
        *(bf16x8*)(Ab + addr) = v;
    }
    {
        int g = tid >> 3, l8 = tid & 7;
        int node = dst0 + g;
        bool valid = node < N_NODES;
        const ushort* xcol = X1b + l8 * 8;
        int lo = valid ? rstart[node * NREL] : 0;
        for (int r = 0; r < NREL; ++r) {
            int hi = valid ? rstart[node * NREL + r + 1] : 0;
            float acc[8] = {0.f, 0.f, 0.f, 0.f, 0.f, 0.f, 0.f, 0.f};
            int cnt = hi - lo;
            for (int e = lo; e < hi; ++e) {
                int src = sedge[e];
                bf16x8 v = *(const bf16x8*)(xcol + (size_t)src * HID);
#pragma unroll
                for (int j = 0; j < 8; ++j) acc[j] += bf2f((unsigned short)v[j]);
            }
            float s = (cnt > 0) ? 1.0f / (float)cnt : 0.0f;
            bf16x8 o;
#pragma unroll
            for (int j = 0; j < 8; ++j) o[j] = (short)f2bf(acc[j] * s);
            int addr = (((r * TILE + g) << 7) + (l8 << 4)) ^ ((g & 7) << 4);
            *(bf16x8*)(Ab + addr) = o;
            lo = hi;
        }
    }
    __syncthreads();

    // --- MFMA: out cols = 16 only, so waves split the 17 tasks (w, w+4, ...)
    int wave = tid >> 6, lane = tid & 63;
    int mr = lane & 15, kq = lane >> 4;
    f32x4 c0 = {0.f, 0.f, 0.f, 0.f}, c1 = {0.f, 0.f, 0.f, 0.f};
    const ushort* wb = WbT2 + mr * HID + kq * 8;
    int sw = (mr & 7) << 4;
    int a00o = ((mr << 7) + (kq << 4)) ^ sw;
    int a01o = ((mr << 7) + 64 + (kq << 4)) ^ sw;
    int a10o = (((16 + mr) << 7) + (kq << 4)) ^ sw;
    int a11o = (((16 + mr) << 7) + 64 + (kq << 4)) ^ sw;
    for (int t = wave; t < 17; t += 4) {
        bf16x8 bk0 = *(const bf16x8*)(wb + t * 1024);
        bf16x8 bk1 = *(const bf16x8*)(wb + t * 1024 + 32);
        const char* At = Ab + t * (TILE * 128);
        bf16x8 a00 = *(const bf16x8*)(At + a00o);
        bf16x8 a01 = *(const bf16x8*)(At + a01o);
        bf16x8 a10 = *(const bf16x8*)(At + a10o);
        bf16x8 a11 = *(const bf16x8*)(At + a11o);
        c0 = __builtin_amdgcn_mfma_f32_16x16x32_bf16(a00, bk0, c0, 0, 0, 0);
        c0 = __builtin_amdgcn_mfma_f32_16x16x32_bf16(a01, bk1, c0, 0, 0, 0);
        c1 = __builtin_amdgcn_mfma_f32_16x16x32_bf16(a10, bk0, c1, 0, 0, 0);
        c1 = __builtin_amdgcn_mfma_f32_16x16x32_bf16(a11, bk1, c1, 0, 0, 0);
    }
    float* Pw = P + wave * (TILE * NCLS);
#pragma unroll
    for (int j = 0; j < 4; ++j) {
        Pw[(kq * 4 + j) * NCLS + mr] = c0[j];
        Pw[(16 + kq * 4 + j) * NCLS + mr] = c1[j];
    }
    __syncthreads();

    // --- cross-wave reduce + bias; 256 threads x 2 consecutive f32
    int idx = tid * 2;
    int row = idx >> 4, c = idx & 15;
    float s0 = P[idx] + P[512 + idx] + P[1024 + idx] + P[1536 + idx] + b2[c];
    float s1 = P[idx + 1] + P[512 + idx + 1] + P[1024 + idx + 1] +
               P[1536 + idx + 1] + b2[c + 1];
    if (dst0 + row < N_NODES) {
        float2 o = make_float2(s0, s1);
        *(float2*)(out + (size_t)(dst0 + row) * NCLS + c) = o;
    }
}

extern "C" void kernel_launch(void* const* d_in, const int* in_sizes, int n_in,
                              void* d_out, int out_size, void* d_ws, size_t ws_size,
                              hipStream_t stream) {
    const int* ei    = (const int*)d_in[0];
    const int* et    = (const int*)d_in[1];
    const float* x   = (const float*)d_in[2];
    const float* W1  = (const float*)d_in[3];
    const float* r1  = (const float*)d_in[4];
    const float* b1  = (const float*)d_in[5];
    const float* W2  = (const float*)d_in[6];
    const float* r2  = (const float*)d_in[7];
    const float* b2  = (const float*)d_in[8];
    float* out = (float*)d_out;

    int E = in_sizes[0] / 2;
    const int* srcp = ei;
    const int* dstp = ei + E;

    int*    bcnt  = (int*)d_ws;                 // doubles as rstart after scan3
    int*    rank  = bcnt + (NBKT + 20);
    int*    bsum  = rank + E;                   // 512 ints (NSB=391 used)
    int*    sedge = bsum + 512;
    ushort* WbT1  = (ushort*)(sedge + E);
    ushort* WbT2  = WbT1 + W1N;
    ushort* xb    = WbT2 + W2N;
    ushort* X1b   = xb + (size_t)N_NODES * HID;
    int*    rstart = bcnt;                      // alias (in-place scan)

    hipMemsetAsync(bcnt, 0, (NBKT + 20) * sizeof(int), stream);

    int eb = (E + 255) / 256;
    int cvtThreads = XCHUNKS + W1N + W2N;

    cvt_k<<<(cvtThreads + 255) / 256, 256, 0, stream>>>(x, W1, r1, W2, r2, xb, WbT1, WbT2);
    rank_k<<<eb, 256, 0, stream>>>(dstp, et, bcnt, rank, E);
    scan1_k<<<NSB, 256, 0, stream>>>(bcnt, bsum);
    scan2_k<<<1, 512, 0, stream>>>(bsum, rstart, E);
    scan3_k<<<NSB, 256, 0, stream>>>(bcnt, bsum);
    scat_k<<<eb, 256, 0, stream>>>(srcp, dstp, et, rank, rstart, sedge, E);

    fuse1_k<<<NTB, 256, 0, stream>>>(xb, sedge, rstart, WbT1, b1, X1b);
    fuse2_k<<<NTB, 256, 0, stream>>>(X1b, sedge, rstart, WbT2, b2, out);
}

// Round 2
// 285.141 us; speedup vs baseline: 1.4477x; 1.4477x over previous
//
#include <hip/hip_runtime.h>
#include <hip/hip_bf16.h>

#define N_NODES 50000
#define NREL 16
#define HID 64
#define NCLS 16
#define NBKT (N_NODES * NREL)       // 800000 buckets (dst*16 + rel)
#define SB 2048                     // scan elems per block
#define NSB ((NBKT + SB - 1) / SB)  // 391
#define TILE 32                     // dst nodes per fused block
#define NTB ((N_NODES + TILE - 1) / TILE)  // 1563
#define XCHUNKS (N_NODES * HID / 8)        // 400000
#define W1N (17 * HID * HID)               // 69632
#define W2N (17 * NCLS * HID)              // 17408

typedef __attribute__((ext_vector_type(8))) short bf16x8;
typedef __attribute__((ext_vector_type(4))) float f32x4;

static __device__ __forceinline__ unsigned short f2bf(float f) {
    __hip_bfloat16 h = __float2bfloat16(f);
    return *reinterpret_cast<unsigned short*>(&h);
}
static __device__ __forceinline__ float bf2f(unsigned short u) {
    __hip_bfloat16 h;
    *reinterpret_cast<unsigned short*>(&h) = u;
    return __bfloat162float(h);
}

// ---------------------------------------------------------------------------
// ws layout:
//   bcnt/rstart i32[800020] (zeroed; scan3 -> prefix IN PLACE)
//   | rank i32[E] | bsum i32[512] | sedge i32[E] (src | rel<<16)
//   | WbT1 bf16[17*64*64] [t][n][k] | WbT2 bf16[17*16*64] [t][n][k]
//   | xb bf16[50000*64] | X1b bf16[50000*64]
// Aggregate-then-transform. Gather is MLP-structured: per node, one pass over
// its contiguous edge range, 32 edge descriptors prefetched in 4 parallel
// loads, flush-on-rel-change (edges rel-sorted within node).
// ---------------------------------------------------------------------------

// K0: convert x -> bf16 AND build transposed bf16 weights (merged grid)
__global__ __launch_bounds__(256) void cvt_k(const float* __restrict__ x,
                                             const float* __restrict__ W1,
                                             const float* __restrict__ root1,
                                             const float* __restrict__ W2,
                                             const float* __restrict__ root2,
                                             ushort* __restrict__ xb,
                                             ushort* __restrict__ WbT1,
                                             ushort* __restrict__ WbT2) {
    int i = blockIdx.x * 256 + threadIdx.x;
    if (i < XCHUNKS) {
        float4 f0 = *(const float4*)(x + (size_t)i * 8);
        float4 f1 = *(const float4*)(x + (size_t)i * 8 + 4);
        bf16x8 o;
        o[0] = (short)f2bf(f0.x); o[1] = (short)f2bf(f0.y);
        o[2] = (short)f2bf(f0.z); o[3] = (short)f2bf(f0.w);
        o[4] = (short)f2bf(f1.x); o[5] = (short)f2bf(f1.y);
        o[6] = (short)f2bf(f1.z); o[7] = (short)f2bf(f1.w);
        *(bf16x8*)(xb + (size_t)i * 8) = o;
    } else {
        int j = i - XCHUNKS;
        if (j < W1N) {
            int t = j >> 12, rem = j & 4095, n = rem >> 6, k = rem & 63;
            float v = (t < 16) ? W1[(size_t)t * HID * HID + k * HID + n]
                               : root1[k * HID + n];
            WbT1[j] = f2bf(v);
        } else {
            int m = j - W1N;
            if (m < W2N) {
                int t = m >> 10, rem = m & 1023, n = rem >> 6, k = rem & 63;
                float v = (t < 16) ? W2[(size_t)t * HID * NCLS + k * NCLS + n]
                                   : root2[k * NCLS + n];
                WbT2[m] = f2bf(v);
            }
        }
    }
}

// K1: one atomic pass over buckets (dst*16+rel): count + per-edge rank
__global__ __launch_bounds__(256) void rank_k(const int* __restrict__ dstp,
                                              const int* __restrict__ et,
                                              int* __restrict__ bcnt,
                                              int* __restrict__ rank, int E) {
    int i = blockIdx.x * 256 + threadIdx.x;
    if (i < E) {
        int b = dstp[i] * NREL + et[i];
        rank[i] = atomicAdd(&bcnt[b], 1);
    }
}

// K2a: per-block sums of bcnt (2048 elems / block, 8 per thread)
__global__ __launch_bounds__(256) void scan1_k(const int* __restrict__ bcnt,
                                               int* __restrict__ bsum) {
    int b = blockIdx.x, t = threadIdx.x;
    int base = b * SB + t * 8;
    int s = 0;
#pragma unroll
    for (int j = 0; j < 8; ++j)
        if (base + j < NBKT) s += bcnt[base + j];
#pragma unroll
    for (int off = 1; off < 64; off <<= 1) s += __shfl_xor(s, off, 64);
    __shared__ int ws[4];
    if ((t & 63) == 0) ws[t >> 6] = s;
    __syncthreads();
    if (t == 0) bsum[b] = ws[0] + ws[1] + ws[2] + ws[3];
}

// K2b: exclusive scan of bsum[NSB] (one 512-thread block); rstart[NBKT] = E
__global__ __launch_bounds__(512) void scan2_k(int* __restrict__ bsum,
                                               int* __restrict__ rstart, int E) {
    __shared__ int ts[512];
    int t = threadIdx.x;
    int v = (t < NSB) ? bsum[t] : 0;
    ts[t] = v;
    __syncthreads();
    int acc = v;
    for (int off = 1; off < 512; off <<= 1) {
        int u = (t >= off) ? ts[t - off] : 0;
        __syncthreads();
        acc += u;
        ts[t] = acc;
        __syncthreads();
    }
    if (t < NSB) bsum[t] = acc - v;
    if (t == 0) rstart[NBKT] = E;
}

// K2c: per-block exclusive scan, IN PLACE (bcnt -> rstart)
__global__ __launch_bounds__(256) void scan3_k(int* __restrict__ bcnt,
                                               const int* __restrict__ bsum) {
    int b = blockIdx.x, t = threadIdx.x;
    int base = b * SB + t * 8;
    int a[8];
    int s = 0;
#pragma unroll
    for (int j = 0; j < 8; ++j) {
        a[j] = (base + j < NBKT) ? bcnt[base + j] : 0;
        s += a[j];
    }
    __shared__ int ts[256];
    ts[t] = s;
    __syncthreads();
    int acc = s;
    for (int off = 1; off < 256; off <<= 1) {
        int u = (t >= off) ? ts[t - off] : 0;
        __syncthreads();
        acc += u;
        ts[t] = acc;
        __syncthreads();
    }
    int run = bsum[b] + (acc - s);
#pragma unroll
    for (int j = 0; j < 8; ++j) {
        if (base + j < NBKT) bcnt[base + j] = run;
        run += a[j];
    }
}

// K3: atomic-free scatter; pack src (16b) | rel<<16
__global__ __launch_bounds__(256) void scat_k(const int* __restrict__ srcp,
                                              const int* __restrict__ dstp,
                                              const int* __restrict__ et,
                                              const int* __restrict__ rank,
                                              const int* __restrict__ rstart,
                                              int* __restrict__ sedge, int E) {
    int i = blockIdx.x * 256 + threadIdx.x;
    if (i < E) {
        int r = et[i];
        int b = dstp[i] * NREL + r;
        sedge[rstart[b] + rank[i]] = srcp[i] | (r << 16);
    }
}

// ---------------------------------------------------------------------------
// Fused layer kernels. Per 32-dst tile: build A[17][32][64] bf16 in LDS
// (16 relation means + root), MFMA against all 17 weight slices.
// LDS rows are 128 B -> XOR swizzle byte^=((row&7)<<4) both sides.
// Gather: group of 8 lanes per dst row; one pass over the node's contiguous
// edge range; 32 descriptors prefetched in 4 parallel loads + __shfl
// broadcast; flush accumulator to LDS on relation change (run-length = cnt).
// ---------------------------------------------------------------------------

#define FLUSH(J)                                                              \
    {                                                                         \
        int cnt_ = (J)-cstart;                                                \
        if (cnt_ > 0) {                                                       \
            float s_ = 1.0f / (float)cnt_;                                    \
            bf16x8 o_;                                                        \
            o_[0] = (short)f2bf(acc[0] * s_); o_[1] = (short)f2bf(acc[1] * s_); \
            o_[2] = (short)f2bf(acc[2] * s_); o_[3] = (short)f2bf(acc[3] * s_); \
            o_[4] = (short)f2bf(acc[4] * s_); o_[5] = (short)f2bf(acc[5] * s_); \
            o_[6] = (short)f2bf(acc[6] * s_); o_[7] = (short)f2bf(acc[7] * s_); \
            *(bf16x8*)(Ab + ((curRel * (TILE * 128) + rowoff) ^ sw)) = o_;    \
            acc[0] = 0.f; acc[1] = 0.f; acc[2] = 0.f; acc[3] = 0.f;           \
            acc[4] = 0.f; acc[5] = 0.f; acc[6] = 0.f; acc[7] = 0.f;           \
        }                                                                     \
    }

// Shared gather: fills Ab[17][32][64] (swizzled) from feature table ft.
static __device__ __forceinline__ void gather_tile(char* Ab,
                                                   const ushort* __restrict__ ft,
                                                   const int* __restrict__ sedge,
                                                   const int* __restrict__ rstart,
                                                   int dst0, int tid) {
    int g = tid >> 3, l8 = tid & 7;
    int lane = tid & 63;
    int gbase = lane & 56;
    int node = dst0 + g;
    bool valid = node < N_NODES;

    int lo = 0, hi = 0;
    if (valid) {
        lo = rstart[node * NREL];
        hi = rstart[node * NREL + NREL];
    }

    int sw = (g & 7) << 4;
    int rowoff = (g << 7) + (l8 << 4);
    const bf16x8 zz = {0, 0, 0, 0, 0, 0, 0, 0};
#pragma unroll
    for (int t = 0; t < 16; ++t)
        *(bf16x8*)(Ab + ((t * (TILE * 128) + rowoff) ^ sw)) = zz;

    // prefetch up to 32 packed edge descriptors (4 parallel loads/lane-group)
    int e0 = 0, e1 = 0, e2 = 0, e3 = 0;
    int p = lo + l8;
    if (p < hi) e0 = sedge[p];
    if (p + 8 < hi) e1 = sedge[p + 8];
    if (p + 16 < hi) e2 = sedge[p + 16];
    if (p + 24 < hi) e3 = sedge[p + 24];

    // root row (t=16)
    {
        bf16x8 v = zz;
        if (valid) v = *(const bf16x8*)(ft + (size_t)node * HID + l8 * 8);
        *(bf16x8*)(Ab + ((16 * (TILE * 128) + rowoff) ^ sw)) = v;
    }

    int deg = hi - lo;
    const ushort* xcol = ft + l8 * 8;
    float acc[8] = {0.f, 0.f, 0.f, 0.f, 0.f, 0.f, 0.f, 0.f};
    int curRel = 0, cstart = 0;

#pragma unroll
    for (int jb = 0; jb < 4; ++jb) {
        int ev = (jb == 0) ? e0 : (jb == 1) ? e1 : (jb == 2) ? e2 : e3;
#pragma unroll
        for (int j8 = 0; j8 < 8; ++j8) {
            int j = jb * 8 + j8;
            int val = __shfl(ev, gbase + j8, 64);
            if (j < deg) {
                int r = (val >> 16) & 15;
                if (r != curRel) {
                    FLUSH(j);
                    curRel = r;
                    cstart = j;
                }
                bf16x8 v = *(const bf16x8*)(xcol + (size_t)(val & 0xFFFF) * HID);
#pragma unroll
                for (int q = 0; q < 8; ++q) acc[q] += bf2f((unsigned short)v[q]);
            }
        }
    }
    // rare tail (deg > 32)
    for (int e = lo + 32; e < hi; ++e) {
        int val = sedge[e];
        int j = e - lo;
        int r = (val >> 16) & 15;
        if (r != curRel) {
            FLUSH(j);
            curRel = r;
            cstart = j;
        }
        bf16x8 v = *(const bf16x8*)(xcol + (size_t)(val & 0xFFFF) * HID);
#pragma unroll
        for (int q = 0; q < 8; ++q) acc[q] += bf2f((unsigned short)v[q]);
    }
    if (deg > 0) FLUSH(deg);
}

__global__ __launch_bounds__(256) void fuse1_k(const ushort* __restrict__ xb,
                                               const int* __restrict__ sedge,
                                               const int* __restrict__ rstart,
                                               const ushort* __restrict__ WbT1,
                                               const float* __restrict__ b1,
                                               ushort* __restrict__ X1b) {
    __shared__ bf16x8 Abuf[17 * TILE * 8];  // 69632 B
    char* Ab = (char*)Abuf;
    int tid = threadIdx.x;
    int dst0 = blockIdx.x * TILE;

    gather_tile(Ab, xb, sedge, rstart, dst0, tid);
    __syncthreads();

    // --- MFMA: wave w owns out cols [w*16, w*16+16), both 16-row m-tiles
    int wave = tid >> 6, lane = tid & 63;
    int mr = lane & 15, kq = lane >> 4;
    f32x4 c0 = {0.f, 0.f, 0.f, 0.f}, c1 = {0.f, 0.f, 0.f, 0.f};
    const ushort* wb = WbT1 + (wave * 16 + mr) * HID + kq * 8;
    int sw = (mr & 7) << 4;
    int a00o = ((mr << 7) + (kq << 4)) ^ sw;
    int a01o = ((mr << 7) + 64 + (kq << 4)) ^ sw;
    int a10o = (((16 + mr) << 7) + (kq << 4)) ^ sw;  // (16+mr)&7 == mr&7
    int a11o = (((16 + mr) << 7) + 64 + (kq << 4)) ^ sw;
    for (int t = 0; t < 17; ++t) {
        bf16x8 bk0 = *(const bf16x8*)(wb + t * 4096);
        bf16x8 bk1 = *(const bf16x8*)(wb + t * 4096 + 32);
        const char* At = Ab + t * (TILE * 128);
        bf16x8 a00 = *(const bf16x8*)(At + a00o);
        bf16x8 a01 = *(const bf16x8*)(At + a01o);
        bf16x8 a10 = *(const bf16x8*)(At + a10o);
        bf16x8 a11 = *(const bf16x8*)(At + a11o);
        c0 = __builtin_amdgcn_mfma_f32_16x16x32_bf16(a00, bk0, c0, 0, 0, 0);
        c0 = __builtin_amdgcn_mfma_f32_16x16x32_bf16(a01, bk1, c0, 0, 0, 0);
        c1 = __builtin_amdgcn_mfma_f32_16x16x32_bf16(a10, bk0, c1, 0, 0, 0);
        c1 = __builtin_amdgcn_mfma_f32_16x16x32_bf16(a11, bk1, c1, 0, 0, 0);
    }
    float bias = b1[wave * 16 + mr];
    int col = wave * 16 + mr;
#pragma unroll
    for (int j = 0; j < 4; ++j) {
        int r0 = dst0 + kq * 4 + j;  // D row = quad*4+reg
        if (r0 < N_NODES)
            X1b[(size_t)r0 * HID + col] = f2bf(fmaxf(c0[j] + bias, 0.f));
        int r1 = r0 + 16;
        if (r1 < N_NODES)
            X1b[(size_t)r1 * HID + col] = f2bf(fmaxf(c1[j] + bias, 0.f));
    }
}

__global__ __launch_bounds__(256) void fuse2_k(const ushort* __restrict__ X1b,
                                               const int* __restrict__ sedge,
                                               const int* __restrict__ rstart,
                                               const ushort* __restrict__ WbT2,
                                               const float* __restrict__ b2,
                                               float* __restrict__ out) {
    __shared__ bf16x8 Abuf[17 * TILE * 8];  // 69632 B
    __shared__ float P[4 * TILE * NCLS];    // 8192 B partials (per-wave)
    char* Ab = (char*)Abuf;
    int tid = threadIdx.x;
    int dst0 = blockIdx.x * TILE;

    gather_tile(Ab, X1b, sedge, rstart, dst0, tid);
    __syncthreads();

    // --- MFMA: out cols = 16 only, so waves split the 17 tasks (w, w+4, ...)
    int wave = tid >> 6, lane = tid & 63;
    int mr = lane & 15, kq = lane >> 4;
    f32x4 c0 = {0.f, 0.f, 0.f, 0.f}, c1 = {0.f, 0.f, 0.f, 0.f};
    const ushort* wb = WbT2 + mr * HID + kq * 8;
    int sw = (mr & 7) << 4;
    int a00o = ((mr << 7) + (kq << 4)) ^ sw;
    int a01o = ((mr << 7) + 64 + (kq << 4)) ^ sw;
    int a10o = (((16 + mr) << 7) + (kq << 4)) ^ sw;
    int a11o = (((16 + mr) << 7) + 64 + (kq << 4)) ^ sw;
    for (int t = wave; t < 17; t += 4) {
        bf16x8 bk0 = *(const bf16x8*)(wb + t * 1024);
        bf16x8 bk1 = *(const bf16x8*)(wb + t * 1024 + 32);
        const char* At = Ab + t * (TILE * 128);
        bf16x8 a00 = *(const bf16x8*)(At + a00o);
        bf16x8 a01 = *(const bf16x8*)(At + a01o);
        bf16x8 a10 = *(const bf16x8*)(At + a10o);
        bf16x8 a11 = *(const bf16x8*)(At + a11o);
        c0 = __builtin_amdgcn_mfma_f32_16x16x32_bf16(a00, bk0, c0, 0, 0, 0);
        c0 = __builtin_amdgcn_mfma_f32_16x16x32_bf16(a01, bk1, c0, 0, 0, 0);
        c1 = __builtin_amdgcn_mfma_f32_16x16x32_bf16(a10, bk0, c1, 0, 0, 0);
        c1 = __builtin_amdgcn_mfma_f32_16x16x32_bf16(a11, bk1, c1, 0, 0, 0);
    }
    float* Pw = P + wave * (TILE * NCLS);
#pragma unroll
    for (int j = 0; j < 4; ++j) {
        Pw[(kq * 4 + j) * NCLS + mr] = c0[j];
        Pw[(16 + kq * 4 + j) * NCLS + mr] = c1[j];
    }
    __syncthreads();

    // --- cross-wave reduce + bias; 256 threads x 2 consecutive f32
    int idx = tid * 2;
    int row = idx >> 4, c = idx & 15;
    float s0 = P[idx] + P[512 + idx] + P[1024 + idx] + P[1536 + idx] + b2[c];
    float s1 = P[idx + 1] + P[512 + idx + 1] + P[1024 + idx + 1] +
               P[1536 + idx + 1] + b2[c + 1];
    if (dst0 + row < N_NODES) {
        float2 o = make_float2(s0, s1);
        *(float2*)(out + (size_t)(dst0 + row) * NCLS + c) = o;
    }
}

extern "C" void kernel_launch(void* const* d_in, const int* in_sizes, int n_in,
                              void* d_out, int out_size, void* d_ws, size_t ws_size,
                              hipStream_t stream) {
    const int* ei    = (const int*)d_in[0];
    const int* et    = (const int*)d_in[1];
    const float* x   = (const float*)d_in[2];
    const float* W1  = (const float*)d_in[3];
    const float* r1  = (const float*)d_in[4];
    const float* b1  = (const float*)d_in[5];
    const float* W2  = (const float*)d_in[6];
    const float* r2  = (const float*)d_in[7];
    const float* b2  = (const float*)d_in[8];
    float* out = (float*)d_out;

    int E = in_sizes[0] / 2;
    const int* srcp = ei;
    const int* dstp = ei + E;

    int*    bcnt  = (int*)d_ws;                 // doubles as rstart after scan3
    int*    rank  = bcnt + (NBKT + 20);
    int*    bsum  = rank + E;                   // 512 ints (NSB=391 used)
    int*    sedge = bsum + 512;
    ushort* WbT1  = (ushort*)(sedge + E);
    ushort* WbT2  = WbT1 + W1N;
    ushort* xb    = WbT2 + W2N;
    ushort* X1b   = xb + (size_t)N_NODES * HID;
    int*    rstart = bcnt;                      // alias (in-place scan)

    hipMemsetAsync(bcnt, 0, (NBKT + 20) * sizeof(int), stream);

    int eb = (E + 255) / 256;
    int cvtThreads = XCHUNKS + W1N + W2N;

    cvt_k<<<(cvtThreads + 255) / 256, 256, 0, stream>>>(x, W1, r1, W2, r2, xb, WbT1, WbT2);
    rank_k<<<eb, 256, 0, stream>>>(dstp, et, bcnt, rank, E);
    scan1_k<<<NSB, 256, 0, stream>>>(bcnt, bsum);
    scan2_k<<<1, 512, 0, stream>>>(bsum, rstart, E);
    scan3_k<<<NSB, 256, 0, stream>>>(bcnt, bsum);
    scat_k<<<eb, 256, 0, stream>>>(srcp, dstp, et, rank, rstart, sedge, E);

    fuse1_k<<<NTB, 256, 0, stream>>>(xb, sedge, rstart, WbT1, b1, X1b);
    fuse2_k<<<NTB, 256, 0, stream>>>(X1b, sedge, rstart, WbT2, b2, out);
}

// Round 3
// 244.685 us; speedup vs baseline: 1.6871x; 1.1653x over previous
//
#include <hip/hip_runtime.h>
#include <hip/hip_bf16.h>

#define N_NODES 50000
#define NREL 16
#define HID 64
#define NCLS 16
#define NBKT (N_NODES * NREL)       // 800000 buckets (dst*16 + rel)
#define SB 2048                     // scan elems per block
#define NSB ((NBKT + SB - 1) / SB)  // 391
#define TILE 32                     // dst nodes per fused block
#define NTB ((N_NODES + TILE - 1) / TILE)  // 1563
#define XCHUNKS (N_NODES * HID / 8)        // 400000
#define W1N (17 * HID * HID)               // 69632
#define W2N (17 * NCLS * HID)              // 17408

typedef __attribute__((ext_vector_type(8))) short bf16x8;
typedef __attribute__((ext_vector_type(4))) float f32x4;

static __device__ __forceinline__ unsigned short f2bf(float f) {
    __hip_bfloat16 h = __float2bfloat16(f);
    return *reinterpret_cast<unsigned short*>(&h);
}
static __device__ __forceinline__ float bf2f(unsigned short u) {
    __hip_bfloat16 h;
    *reinterpret_cast<unsigned short*>(&h) = u;
    return __bfloat162float(h);
}

// ---------------------------------------------------------------------------
// ws layout:
//   bcnt/rstart i32[800020] (zeroed; scan3 -> prefix IN PLACE)
//   | rank i32[E] | bsum i32[512] | sedge i32[E] (src | rel<<16)
//   | WbT1 bf16[17*64*64] [t][n][k] | WbT2 bf16[17*16*64] [t][n][k]
//   | xb bf16[50000*64] | X1b bf16[50000*64]
// Aggregate-then-transform. Gather: per node one pass over its contiguous
// edge range; 32 descriptors prefetched; feature loads BATCHED 8-wide and
// software-pipelined 2-deep so each block exposes ~3 memory round-trips
// instead of ~32.
// ---------------------------------------------------------------------------

// K0: convert x -> bf16 AND build transposed bf16 weights (merged grid)
__global__ __launch_bounds__(256) void cvt_k(const float* __restrict__ x,
                                             const float* __restrict__ W1,
                                             const float* __restrict__ root1,
                                             const float* __restrict__ W2,
                                             const float* __restrict__ root2,
                                             ushort* __restrict__ xb,
                                             ushort* __restrict__ WbT1,
                                             ushort* __restrict__ WbT2) {
    int i = blockIdx.x * 256 + threadIdx.x;
    if (i < XCHUNKS) {
        float4 f0 = *(const float4*)(x + (size_t)i * 8);
        float4 f1 = *(const float4*)(x + (size_t)i * 8 + 4);
        bf16x8 o;
        o[0] = (short)f2bf(f0.x); o[1] = (short)f2bf(f0.y);
        o[2] = (short)f2bf(f0.z); o[3] = (short)f2bf(f0.w);
        o[4] = (short)f2bf(f1.x); o[5] = (short)f2bf(f1.y);
        o[6] = (short)f2bf(f1.z); o[7] = (short)f2bf(f1.w);
        *(bf16x8*)(xb + (size_t)i * 8) = o;
    } else {
        int j = i - XCHUNKS;
        if (j < W1N) {
            int t = j >> 12, rem = j & 4095, n = rem >> 6, k = rem & 63;
            float v = (t < 16) ? W1[(size_t)t * HID * HID + k * HID + n]
                               : root1[k * HID + n];
            WbT1[j] = f2bf(v);
        } else {
            int m = j - W1N;
            if (m < W2N) {
                int t = m >> 10, rem = m & 1023, n = rem >> 6, k = rem & 63;
                float v = (t < 16) ? W2[(size_t)t * HID * NCLS + k * NCLS + n]
                                   : root2[k * NCLS + n];
                WbT2[m] = f2bf(v);
            }
        }
    }
}

// K1: one atomic pass over buckets (dst*16+rel): count + per-edge rank
__global__ __launch_bounds__(256) void rank_k(const int* __restrict__ dstp,
                                              const int* __restrict__ et,
                                              int* __restrict__ bcnt,
                                              int* __restrict__ rank, int E) {
    int i = blockIdx.x * 256 + threadIdx.x;
    if (i < E) {
        int b = dstp[i] * NREL + et[i];
        rank[i] = atomicAdd(&bcnt[b], 1);
    }
}

// K2a: per-block sums of bcnt (2048 elems / block, 8 per thread)
__global__ __launch_bounds__(256) void scan1_k(const int* __restrict__ bcnt,
                                               int* __restrict__ bsum) {
    int b = blockIdx.x, t = threadIdx.x;
    int base = b * SB + t * 8;
    int s = 0;
#pragma unroll
    for (int j = 0; j < 8; ++j)
        if (base + j < NBKT) s += bcnt[base + j];
#pragma unroll
    for (int off = 1; off < 64; off <<= 1) s += __shfl_xor(s, off, 64);
    __shared__ int ws[4];
    if ((t & 63) == 0) ws[t >> 6] = s;
    __syncthreads();
    if (t == 0) bsum[b] = ws[0] + ws[1] + ws[2] + ws[3];
}

// K2b: exclusive scan of bsum[NSB] (one 512-thread block); rstart[NBKT] = E
__global__ __launch_bounds__(512) void scan2_k(int* __restrict__ bsum,
                                               int* __restrict__ rstart, int E) {
    __shared__ int ts[512];
    int t = threadIdx.x;
    int v = (t < NSB) ? bsum[t] : 0;
    ts[t] = v;
    __syncthreads();
    int acc = v;
    for (int off = 1; off < 512; off <<= 1) {
        int u = (t >= off) ? ts[t - off] : 0;
        __syncthreads();
        acc += u;
        ts[t] = acc;
        __syncthreads();
    }
    if (t < NSB) bsum[t] = acc - v;
    if (t == 0) rstart[NBKT] = E;
}

// K2c: per-block exclusive scan, IN PLACE (bcnt -> rstart)
__global__ __launch_bounds__(256) void scan3_k(int* __restrict__ bcnt,
                                               const int* __restrict__ bsum) {
    int b = blockIdx.x, t = threadIdx.x;
    int base = b * SB + t * 8;
    int a[8];
    int s = 0;
#pragma unroll
    for (int j = 0; j < 8; ++j) {
        a[j] = (base + j < NBKT) ? bcnt[base + j] : 0;
        s += a[j];
    }
    __shared__ int ts[256];
    ts[t] = s;
    __syncthreads();
    int acc = s;
    for (int off = 1; off < 256; off <<= 1) {
        int u = (t >= off) ? ts[t - off] : 0;
        __syncthreads();
        acc += u;
        ts[t] = acc;
        __syncthreads();
    }
    int run = bsum[b] + (acc - s);
#pragma unroll
    for (int j = 0; j < 8; ++j) {
        if (base + j < NBKT) bcnt[base + j] = run;
        run += a[j];
    }
}

// K3: atomic-free scatter; pack src (16b) | rel<<16
__global__ __launch_bounds__(256) void scat_k(const int* __restrict__ srcp,
                                              const int* __restrict__ dstp,
                                              const int* __restrict__ et,
                                              const int* __restrict__ rank,
                                              const int* __restrict__ rstart,
                                              int* __restrict__ sedge, int E) {
    int i = blockIdx.x * 256 + threadIdx.x;
    if (i < E) {
        int r = et[i];
        int b = dstp[i] * NREL + r;
        sedge[rstart[b] + rank[i]] = srcp[i] | (r << 16);
    }
}

// ---------------------------------------------------------------------------
// Fused layer kernels. Per 32-dst tile: build A[17][32][64] bf16 in LDS
// (16 relation means + root), MFMA against all 17 weight slices.
// LDS rows are 128 B -> XOR swizzle byte^=((row&7)<<4) both sides.
// ---------------------------------------------------------------------------

#define FLUSH(J)                                                              \
    {                                                                         \
        int cnt_ = (J)-cstart;                                                \
        if (cnt_ > 0) {                                                       \
            float s_ = 1.0f / (float)cnt_;                                    \
            bf16x8 o_;                                                        \
            o_[0] = (short)f2bf(acc[0] * s_); o_[1] = (short)f2bf(acc[1] * s_); \
            o_[2] = (short)f2bf(acc[2] * s_); o_[3] = (short)f2bf(acc[3] * s_); \
            o_[4] = (short)f2bf(acc[4] * s_); o_[5] = (short)f2bf(acc[5] * s_); \
            o_[6] = (short)f2bf(acc[6] * s_); o_[7] = (short)f2bf(acc[7] * s_); \
            *(bf16x8*)(Ab + ((curRel * (TILE * 128) + rowoff) ^ sw)) = o_;    \
            acc[0] = 0.f; acc[1] = 0.f; acc[2] = 0.f; acc[3] = 0.f;           \
            acc[4] = 0.f; acc[5] = 0.f; acc[6] = 0.f; acc[7] = 0.f;           \
        }                                                                     \
    }

// Issue 8 independent predicated feature loads for one 8-edge batch.
#define LOADB(VAL, V, EV, JB)                                                 \
    _Pragma("unroll") for (int j8 = 0; j8 < 8; ++j8) {                        \
        VAL[j8] = __shfl(EV, gbase + j8, 64);                                 \
        V[j8] = zz;                                                           \
        if (JB + j8 < deg)                                                    \
            V[j8] = *(const bf16x8*)(xcol + (size_t)(VAL[j8] & 0xFFFF) * HID);\
    }

// Consume one batch (rel flush-on-change + accumulate).
#define ACCB(VAL, V, JB)                                                      \
    _Pragma("unroll") for (int j8 = 0; j8 < 8; ++j8) {                        \
        int j_ = JB + j8;                                                     \
        if (j_ < deg) {                                                       \
            int r_ = (VAL[j8] >> 16) & 15;                                    \
            if (r_ != curRel) { FLUSH(j_); curRel = r_; cstart = j_; }        \
            _Pragma("unroll") for (int q = 0; q < 8; ++q)                     \
                acc[q] += bf2f((unsigned short)V[j8][q]);                     \
        }                                                                     \
    }

// Shared gather: fills Ab[17][32][64] (swizzled) from feature table ft.
static __device__ __forceinline__ void gather_tile(char* Ab,
                                                   const ushort* __restrict__ ft,
                                                   const int* __restrict__ sedge,
                                                   const int* __restrict__ rstart,
                                                   int dst0, int tid) {
    int g = tid >> 3, l8 = tid & 7;
    int lane = tid & 63;
    int gbase = lane & 56;
    int node = dst0 + g;
    bool valid = node < N_NODES;

    int lo = 0, hi = 0;
    if (valid) {
        lo = rstart[node * NREL];
        hi = rstart[node * NREL + NREL];
    }

    int sw = (g & 7) << 4;
    int rowoff = (g << 7) + (l8 << 4);
    const bf16x8 zz = {0, 0, 0, 0, 0, 0, 0, 0};

    // prefetch up to 32 packed edge descriptors (4 parallel loads/lane-group)
    int e0 = 0, e1 = 0, e2 = 0, e3 = 0;
    int p = lo + l8;
    if (p < hi) e0 = sedge[p];
    if (p + 8 < hi) e1 = sedge[p + 8];
    if (p + 16 < hi) e2 = sedge[p + 16];
    if (p + 24 < hi) e3 = sedge[p + 24];

#pragma unroll
    for (int t = 0; t < 16; ++t)
        *(bf16x8*)(Ab + ((t * (TILE * 128) + rowoff) ^ sw)) = zz;

    // root row (t=16)
    {
        bf16x8 v = zz;
        if (valid) v = *(const bf16x8*)(ft + (size_t)node * HID + l8 * 8);
        *(bf16x8*)(Ab + ((16 * (TILE * 128) + rowoff) ^ sw)) = v;
    }

    int deg = hi - lo;
    const ushort* xcol = ft + l8 * 8;
    float acc[8] = {0.f, 0.f, 0.f, 0.f, 0.f, 0.f, 0.f, 0.f};
    int curRel = 0, cstart = 0;

    // 2-deep pipelined batches: issue A, issue B, consume A, issue A',
    // consume B, issue B', consume A', consume B'.
    int valA[8], valB[8];
    bf16x8 vA[8], vB[8];
    LOADB(valA, vA, e0, 0)
    LOADB(valB, vB, e1, 8)
    ACCB(valA, vA, 0)
    LOADB(valA, vA, e2, 16)
    ACCB(valB, vB, 8)
    LOADB(valB, vB, e3, 24)
    ACCB(valA, vA, 16)
    ACCB(valB, vB, 24)

    // rare tail (deg > 32)
    for (int e = lo + 32; e < hi; ++e) {
        int val = sedge[e];
        int j = e - lo;
        int r = (val >> 16) & 15;
        if (r != curRel) {
            FLUSH(j);
            curRel = r;
            cstart = j;
        }
        bf16x8 v = *(const bf16x8*)(xcol + (size_t)(val & 0xFFFF) * HID);
#pragma unroll
        for (int q = 0; q < 8; ++q) acc[q] += bf2f((unsigned short)v[q]);
    }
    if (deg > 0) FLUSH(deg);
}

__global__ __launch_bounds__(256) void fuse1_k(const ushort* __restrict__ xb,
                                               const int* __restrict__ sedge,
                                               const int* __restrict__ rstart,
                                               const ushort* __restrict__ WbT1,
                                               const float* __restrict__ b1,
                                               ushort* __restrict__ X1b) {
    __shared__ bf16x8 Abuf[17 * TILE * 8];  // 69632 B
    char* Ab = (char*)Abuf;
    int tid = threadIdx.x;
    int dst0 = blockIdx.x * TILE;

    gather_tile(Ab, xb, sedge, rstart, dst0, tid);

    // --- MFMA: wave w owns out cols [w*16, w*16+16), both 16-row m-tiles
    int wave = tid >> 6, lane = tid & 63;
    int mr = lane & 15, kq = lane >> 4;
    f32x4 c0 = {0.f, 0.f, 0.f, 0.f}, c1 = {0.f, 0.f, 0.f, 0.f};
    const ushort* wb = WbT1 + (wave * 16 + mr) * HID + kq * 8;
    int sw = (mr & 7) << 4;
    int a00o = ((mr << 7) + (kq << 4)) ^ sw;
    int a01o = ((mr << 7) + 64 + (kq << 4)) ^ sw;
    int a10o = (((16 + mr) << 7) + (kq << 4)) ^ sw;  // (16+mr)&7 == mr&7
    int a11o = (((16 + mr) << 7) + 64 + (kq << 4)) ^ sw;

    // prefetch t=0 weight fragments before the barrier (overlaps L2 latency)
    bf16x8 bk0 = *(const bf16x8*)(wb);
    bf16x8 bk1 = *(const bf16x8*)(wb + 32);
    __syncthreads();

    for (int t = 0; t < 17; ++t) {
        bf16x8 nb0 = bk0, nb1 = bk1;
        if (t < 16) {
            nb0 = *(const bf16x8*)(wb + (t + 1) * 4096);
            nb1 = *(const bf16x8*)(wb + (t + 1) * 4096 + 32);
        }
        const char* At = Ab + t * (TILE * 128);
        bf16x8 a00 = *(const bf16x8*)(At + a00o);
        bf16x8 a01 = *(const bf16x8*)(At + a01o);
        bf16x8 a10 = *(const bf16x8*)(At + a10o);
        bf16x8 a11 = *(const bf16x8*)(At + a11o);
        c0 = __builtin_amdgcn_mfma_f32_16x16x32_bf16(a00, bk0, c0, 0, 0, 0);
        c0 = __builtin_amdgcn_mfma_f32_16x16x32_bf16(a01, bk1, c0, 0, 0, 0);
        c1 = __builtin_amdgcn_mfma_f32_16x16x32_bf16(a10, bk0, c1, 0, 0, 0);
        c1 = __builtin_amdgcn_mfma_f32_16x16x32_bf16(a11, bk1, c1, 0, 0, 0);
        bk0 = nb0;
        bk1 = nb1;
    }
    float bias = b1[wave * 16 + mr];
    int col = wave * 16 + mr;
#pragma unroll
    for (int j = 0; j < 4; ++j) {
        int r0 = dst0 + kq * 4 + j;  // D row = quad*4+reg
        if (r0 < N_NODES)
            X1b[(size_t)r0 * HID + col] = f2bf(fmaxf(c0[j] + bias, 0.f));
        int r1 = r0 + 16;
        if (r1 < N_NODES)
            X1b[(size_t)r1 * HID + col] = f2bf(fmaxf(c1[j] + bias, 0.f));
    }
}

__global__ __launch_bounds__(256) void fuse2_k(const ushort* __restrict__ X1b,
                                               const int* __restrict__ sedge,
                                               const int* __restrict__ rstart,
                                               const ushort* __restrict__ WbT2,
                                               const float* __restrict__ b2,
                                               float* __restrict__ out) {
    __shared__ bf16x8 Abuf[17 * TILE * 8];  // 69632 B
    __shared__ float P[4 * TILE * NCLS];    // 8192 B partials (per-wave)
    char* Ab = (char*)Abuf;
    int tid = threadIdx.x;
    int dst0 = blockIdx.x * TILE;

    gather_tile(Ab, X1b, sedge, rstart, dst0, tid);

    // --- MFMA: out cols = 16 only, so waves split the 17 tasks (w, w+4, ...)
    int wave = tid >> 6, lane = tid & 63;
    int mr = lane & 15, kq = lane >> 4;
    f32x4 c0 = {0.f, 0.f, 0.f, 0.f}, c1 = {0.f, 0.f, 0.f, 0.f};
    const ushort* wb = WbT2 + mr * HID + kq * 8;
    int sw = (mr & 7) << 4;
    int a00o = ((mr << 7) + (kq << 4)) ^ sw;
    int a01o = ((mr << 7) + 64 + (kq << 4)) ^ sw;
    int a10o = (((16 + mr) << 7) + (kq << 4)) ^ sw;
    int a11o = (((16 + mr) << 7) + 64 + (kq << 4)) ^ sw;

    bf16x8 bk0 = *(const bf16x8*)(wb + wave * 1024);
    bf16x8 bk1 = *(const bf16x8*)(wb + wave * 1024 + 32);
    __syncthreads();

    for (int t = wave; t < 17; t += 4) {
        bf16x8 nb0 = bk0, nb1 = bk1;
        if (t + 4 < 17) {
            nb0 = *(const bf16x8*)(wb + (t + 4) * 1024);
            nb1 = *(const bf16x8*)(wb + (t + 4) * 1024 + 32);
        }
        const char* At = Ab + t * (TILE * 128);
        bf16x8 a00 = *(const bf16x8*)(At + a00o);
        bf16x8 a01 = *(const bf16x8*)(At + a01o);
        bf16x8 a10 = *(const bf16x8*)(At + a10o);
        bf16x8 a11 = *(const bf16x8*)(At + a11o);
        c0 = __builtin_amdgcn_mfma_f32_16x16x32_bf16(a00, bk0, c0, 0, 0, 0);
        c0 = __builtin_amdgcn_mfma_f32_16x16x32_bf16(a01, bk1, c0, 0, 0, 0);
        c1 = __builtin_amdgcn_mfma_f32_16x16x32_bf16(a10, bk0, c1, 0, 0, 0);
        c1 = __builtin_amdgcn_mfma_f32_16x16x32_bf16(a11, bk1, c1, 0, 0, 0);
        bk0 = nb0;
        bk1 = nb1;
    }
    float* Pw = P + wave * (TILE * NCLS);
#pragma unroll
    for (int j = 0; j < 4; ++j) {
        Pw[(kq * 4 + j) * NCLS + mr] = c0[j];
        Pw[(16 + kq * 4 + j) * NCLS + mr] = c1[j];
    }
    __syncthreads();

    // --- cross-wave reduce + bias; 256 threads x 2 consecutive f32
    int idx = tid * 2;
    int row = idx >> 4, c = idx & 15;
    float s0 = P[idx] + P[512 + idx] + P[1024 + idx] + P[1536 + idx] + b2[c];
    float s1 = P[idx + 1] + P[512 + idx + 1] + P[1024 + idx + 1] +
               P[1536 + idx + 1] + b2[c + 1];
    if (dst0 + row < N_NODES) {
        float2 o = make_float2(s0, s1);
        *(float2*)(out + (size_t)(dst0 + row) * NCLS + c) = o;
    }
}

extern "C" void kernel_launch(void* const* d_in, const int* in_sizes, int n_in,
                              void* d_out, int out_size, void* d_ws, size_t ws_size,
                              hipStream_t stream) {
    const int* ei    = (const int*)d_in[0];
    const int* et    = (const int*)d_in[1];
    const float* x   = (const float*)d_in[2];
    const float* W1  = (const float*)d_in[3];
    const float* r1  = (const float*)d_in[4];
    const float* b1  = (const float*)d_in[5];
    const float* W2  = (const float*)d_in[6];
    const float* r2  = (const float*)d_in[7];
    const float* b2  = (const float*)d_in[8];
    float* out = (float*)d_out;

    int E = in_sizes[0] / 2;
    const int* srcp = ei;
    const int* dstp = ei + E;

    int*    bcnt  = (int*)d_ws;                 // doubles as rstart after scan3
    int*    rank  = bcnt + (NBKT + 20);
    int*    bsum  = rank + E;                   // 512 ints (NSB=391 used)
    int*    sedge = bsum + 512;
    ushort* WbT1  = (ushort*)(sedge + E);
    ushort* WbT2  = WbT1 + W1N;
    ushort* xb    = WbT2 + W2N;
    ushort* X1b   = xb + (size_t)N_NODES * HID;
    int*    rstart = bcnt;                      // alias (in-place scan)

    hipMemsetAsync(bcnt, 0, (NBKT + 20) * sizeof(int), stream);

    int eb = (E + 255) / 256;
    int cvtThreads = XCHUNKS + W1N + W2N;

    cvt_k<<<(cvtThreads + 255) / 256, 256, 0, stream>>>(x, W1, r1, W2, r2, xb, WbT1, WbT2);
    rank_k<<<eb, 256, 0, stream>>>(dstp, et, bcnt, rank, E);
    scan1_k<<<NSB, 256, 0, stream>>>(bcnt, bsum);
    scan2_k<<<1, 512, 0, stream>>>(bsum, rstart, E);
    scan3_k<<<NSB, 256, 0, stream>>>(bcnt, bsum);
    scat_k<<<eb, 256, 0, stream>>>(srcp, dstp, et, rank, rstart, sedge, E);

    fuse1_k<<<NTB, 256, 0, stream>>>(xb, sedge, rstart, WbT1, b1, X1b);
    fuse2_k<<<NTB, 256, 0, stream>>>(X1b, sedge, rstart, WbT2, b2, out);
}